// Round 7
// baseline (33.237 us; speedup 1.0000x reference)
//
#include <hip/hip_runtime.h>

#define NUM_ITEMS   1000000
#define DIM         64
#define BATCH       4096
#define MAX_LEN     200
#define INV_TEMP    10.0f

// One WAVE per batch row. 256-thr blocks = 4 independent waves = 4 rows;
// grid 1024 = 4 blocks/CU resident (launch_bounds(256,4): VGPR budget 128,
// so #pragma unroll 10 keeps ~10 row-gathers in flight per wave -> ~160/CU,
// equal MLP to round 6 but with no cross-wave merge, no compaction, and a
// single cheap barrier. Softmax is max-free (|s|/T <= ~64 << 88): pads
// contribute exact 0 via select, matching the reference's -1e9 masking.
__global__ __launch_bounds__(256, 4)
void attn_pool_kernel(const int* __restrict__ hist,      // [BATCH, MAX_LEN]
                      const float* __restrict__ table,   // [NUM_ITEMS, DIM]
                      const float* __restrict__ queries, // [2, DIM]
                      float* __restrict__ out)           // [BATCH, DIM]
{
    __shared__ int sidx[4][MAX_LEN];   // per-wave private strip (3.2 KB)

    const int t    = threadIdx.x;
    const int lane = t & 63;
    const int wave = t >> 6;
    const int b    = blockIdx.x * 4 + wave;   // this wave's batch row
    const int g    = lane >> 4;               // row group 0..3 within wave
    const int c4   = lane & 15;               // float4 column

    // ---- stage this wave's 200 indices into its private LDS strip ----
    const int* hb = hist + (size_t)b * MAX_LEN;
    #pragma unroll
    for (int k = 0; k < 3; ++k) {
        int idx = hb[lane + 64 * k];
        if (idx >= NUM_ITEMS) idx = NUM_ITEMS - 1;   // reference clips high side
        sidx[wave][lane + 64 * k] = idx;
    }
    if (lane < MAX_LEN - 192) {
        int idx = hb[192 + lane];
        if (idx >= NUM_ITEMS) idx = NUM_ITEMS - 1;
        sidx[wave][192 + lane] = idx;
    }
    __syncthreads();   // single barrier: waves arrive together, cost ~0

    const float4 q0 = *reinterpret_cast<const float4*>(&queries[c4 * 4]);
    const float4 q1 = *reinterpret_cast<const float4*>(&queries[DIM + c4 * 4]);

    float  n0 = 0.f, n1 = 0.f;
    float4 a0 = {0.f, 0.f, 0.f, 0.f}, a1 = {0.f, 0.f, 0.f, 0.f};

    // ---- main: 50 unpredicated iterations, 4 rows per wave-iteration ----
    #pragma unroll 10
    for (int it = 0; it < MAX_LEN / 4; ++it) {
        const int idx = sidx[wave][it * 4 + g];   // broadcast within group
        const int row = idx < 0 ? 0 : idx;        // pad -> row 0 (L1-resident)
        const float4 v = *reinterpret_cast<const float4*>(
            &table[(size_t)row * DIM + c4 * 4]);
        float s0 = v.x * q0.x + v.y * q0.y + v.z * q0.z + v.w * q0.w;
        float s1 = v.x * q1.x + v.y * q1.y + v.z * q1.z + v.w * q1.w;
        #pragma unroll
        for (int off = 1; off < 16; off <<= 1) {  // stays inside 16-lane group
            s0 += __shfl_xor(s0, off);
            s1 += __shfl_xor(s1, off);
        }
        const float p0 = (idx < 0) ? 0.f : __expf(s0 * INV_TEMP);
        const float p1 = (idx < 0) ? 0.f : __expf(s1 * INV_TEMP);
        n0 += p0;
        a0.x += p0 * v.x;  a0.y += p0 * v.y;
        a0.z += p0 * v.z;  a0.w += p0 * v.w;
        n1 += p1;
        a1.x += p1 * v.x;  a1.y += p1 * v.y;
        a1.z += p1 * v.z;  a1.w += p1 * v.w;
    }

    // ---- merge the 4 groups (lanes x, x^16, x^32 share c4); pure adds ----
    #pragma unroll
    for (int off = 16; off <= 32; off <<= 1) {
        n0   += __shfl_xor(n0,   off);
        a0.x += __shfl_xor(a0.x, off);  a0.y += __shfl_xor(a0.y, off);
        a0.z += __shfl_xor(a0.z, off);  a0.w += __shfl_xor(a0.w, off);
        n1   += __shfl_xor(n1,   off);
        a1.x += __shfl_xor(a1.x, off);  a1.y += __shfl_xor(a1.y, off);
        a1.z += __shfl_xor(a1.z, off);  a1.w += __shfl_xor(a1.w, off);
    }

    // ---- output: lanes 0..15 hold c4 = lane; one float4 each ----
    if (lane < 16) {
        const float i0 = 1.f / n0, i1 = 1.f / n1;
        float4 o;
        o.x = a0.x * i0 + a1.x * i1;
        o.y = a0.y * i0 + a1.y * i1;
        o.z = a0.z * i0 + a1.z * i1;
        o.w = a0.w * i0 + a1.w * i1;
        *reinterpret_cast<float4*>(&out[(size_t)b * DIM + lane * 4]) = o;
    }
}

extern "C" void kernel_launch(void* const* d_in, const int* in_sizes, int n_in,
                              void* d_out, int out_size, void* d_ws, size_t ws_size,
                              hipStream_t stream) {
    const int*   hist    = (const int*)d_in[0];    // history_indices [4096,200] int32
    const float* table   = (const float*)d_in[1];  // item_table [1000000,64] f32
    const float* queries = (const float*)d_in[2];  // queries [2,64] f32
    float*       out     = (float*)d_out;          // [4096,64] f32

    attn_pool_kernel<<<BATCH / 4, 256, 0, stream>>>(hist, table, queries, out);
}

// Round 8
// 32.177 us; speedup vs baseline: 1.0330x; 1.0330x over previous
//
#include <hip/hip_runtime.h>

#define NUM_ITEMS   1000000
#define DIM         64
#define BATCH       4096
#define MAX_LEN     200
#define INV_TEMP    10.0f

// One block per batch row, 256 threads = 4 waves = 16 row-groups of 16 lanes.
// ~3.6 KB LDS + lean register state -> 8 resident blocks/CU (32 waves/CU):
// ~160+ outstanding 256B gathers per CU, which saturates the memory system's
// random-fetch service rate (rounds 5-7 established: removing fetches, merge,
// or barriers moves <5%; the HBM random-256B service rate ~2.3 TB/s is the wall).
// Valid indices are stream-compacted (ballot + popc prefix); softmax is
// max-free (|s|/T <= ~64 << 88): order-invariant sums n += exp(s/T),
// a += exp(s/T)*v, so compaction order is irrelevant.
__global__ __launch_bounds__(256, 8)
void attn_pool_kernel(const int* __restrict__ hist,      // [BATCH, MAX_LEN]
                      const float* __restrict__ table,   // [NUM_ITEMS, DIM]
                      const float* __restrict__ queries, // [2, DIM]
                      float* __restrict__ out)           // [BATCH, DIM]
{
    __shared__ int   cidx[MAX_LEN];    // compacted valid indices
    __shared__ int   wcnt[4];          // per-wave valid counts
    __shared__ float mrg[4][16][11];   // [wave][c4][10 state + 1 pad]

    const int b    = blockIdx.x;
    const int t    = threadIdx.x;
    const int lane = t & 63;
    const int wave = t >> 6;
    const int g    = t >> 4;    // row group 0..15
    const int c4   = t & 15;    // float4 column

    // ---- Phase 0: load indices, compact valid ones into cidx ----
    int idx = -1;
    if (t < MAX_LEN) {
        idx = hist[b * MAX_LEN + t];
        if (idx >= NUM_ITEMS) idx = NUM_ITEMS - 1;   // reference clips high side
    }
    const bool valid = (idx >= 0);
    const unsigned long long bm = __ballot(valid);   // 64-bit wave mask
    if (lane == 0) wcnt[wave] = __popcll(bm);
    __syncthreads();
    int base = 0, V = 0;
    #pragma unroll
    for (int w = 0; w < 4; ++w) {
        const int c = wcnt[w];
        base += (w < wave) ? c : 0;
        V += c;
    }
    if (valid) {
        const int pre = __popcll(bm & ((1ULL << lane) - 1ULL));
        cidx[base + pre] = idx;
    }
    __syncthreads();

    const float4 q0 = *reinterpret_cast<const float4*>(&queries[c4 * 4]);
    const float4 q1 = *reinterpret_cast<const float4*>(&queries[DIM + c4 * 4]);

    float  n0 = 0.f, n1 = 0.f;
    float4 a0 = {0.f, 0.f, 0.f, 0.f}, a1 = {0.f, 0.f, 0.f, 0.f};

    // ---- Phase 1: fused gather + score + max-free softmax accumulate ----
    #pragma unroll
    for (int it = 0; it < (MAX_LEN + 15) / 16; ++it) {
        const int l = it * 16 + g;
        if (l < V) {
            const int row = cidx[l];                  // LDS broadcast
            const float4 v = *reinterpret_cast<const float4*>(
                &table[(size_t)row * DIM + c4 * 4]);
            float s0 = v.x * q0.x + v.y * q0.y + v.z * q0.z + v.w * q0.w;
            float s1 = v.x * q1.x + v.y * q1.y + v.z * q1.z + v.w * q1.w;
            #pragma unroll
            for (int off = 1; off < 16; off <<= 1) {  // stays inside 16-lane group
                s0 += __shfl_xor(s0, off);
                s1 += __shfl_xor(s1, off);
            }
            const float p0 = __expf(s0 * INV_TEMP);
            const float p1 = __expf(s1 * INV_TEMP);
            n0 += p0;
            a0.x += p0 * v.x;  a0.y += p0 * v.y;
            a0.z += p0 * v.z;  a0.w += p0 * v.w;
            n1 += p1;
            a1.x += p1 * v.x;  a1.y += p1 * v.y;
            a1.z += p1 * v.z;  a1.w += p1 * v.w;
        }
    }

    // ---- intra-wave merge: lanes l, l^16, l^32 share c4; pure adds ----
    #pragma unroll
    for (int off = 16; off <= 32; off <<= 1) {
        n0   += __shfl_xor(n0,   off);
        a0.x += __shfl_xor(a0.x, off);  a0.y += __shfl_xor(a0.y, off);
        a0.z += __shfl_xor(a0.z, off);  a0.w += __shfl_xor(a0.w, off);
        n1   += __shfl_xor(n1,   off);
        a1.x += __shfl_xor(a1.x, off);  a1.y += __shfl_xor(a1.y, off);
        a1.z += __shfl_xor(a1.z, off);  a1.w += __shfl_xor(a1.w, off);
    }

    if (lane < 16) {
        float* s = mrg[wave][c4];
        s[0] = n0;
        s[1] = a0.x; s[2] = a0.y; s[3] = a0.z; s[4] = a0.w;
        s[5] = n1;
        s[6] = a1.x; s[7] = a1.y; s[8] = a1.z; s[9] = a1.w;
    }
    __syncthreads();

    // ---- cross-wave merge + output (16 lanes, one float4 each) ----
    if (t < 16) {
        float  N0 = 0.f, N1 = 0.f;
        float4 A0 = {0.f, 0.f, 0.f, 0.f}, A1 = {0.f, 0.f, 0.f, 0.f};
        #pragma unroll
        for (int w = 0; w < 4; ++w) {
            const float* s = mrg[w][t];
            N0   += s[0];
            A0.x += s[1];  A0.y += s[2];  A0.z += s[3];  A0.w += s[4];
            N1   += s[5];
            A1.x += s[6];  A1.y += s[7];  A1.z += s[8];  A1.w += s[9];
        }
        const float i0 = 1.f / N0, i1 = 1.f / N1;
        float4 o;
        o.x = A0.x * i0 + A1.x * i1;
        o.y = A0.y * i0 + A1.y * i1;
        o.z = A0.z * i0 + A1.z * i1;
        o.w = A0.w * i0 + A1.w * i1;
        *reinterpret_cast<float4*>(&out[b * DIM + t * 4]) = o;
    }
}

extern "C" void kernel_launch(void* const* d_in, const int* in_sizes, int n_in,
                              void* d_out, int out_size, void* d_ws, size_t ws_size,
                              hipStream_t stream) {
    const int*   hist    = (const int*)d_in[0];    // history_indices [4096,200] int32
    const float* table   = (const float*)d_in[1];  // item_table [1000000,64] f32
    const float* queries = (const float*)d_in[2];  // queries [2,64] f32
    float*       out     = (float*)d_out;          // [4096,64] f32

    attn_pool_kernel<<<BATCH, 256, 0, stream>>>(hist, table, queries, out);
}